// Round 1
// 76.596 us; speedup vs baseline: 1.3487x; 1.3487x over previous
//
#include <hip/hip_runtime.h>

// Problem constants
#define FDIM 256
#define BDIM 32
#define MDIM 32768
#define NB   512        // m-tiles (64 m each); one partial per (b, tile)

// ws layout (float units)
#define WS_EM    0                       // (unused after fusion; kept for layout stability)
#define WS_EX    (WS_EM + MDIM*FDIM)
#define WS_W2N   (WS_EX + BDIM*FDIM)
#define WS_PMAX  (WS_W2N + FDIM)
#define WS_PSUM  (WS_PMAX + BDIM*NB)
#define WS_PARG  (WS_PSUM + BDIM*NB)
#define WS_WIN   (WS_PARG + BDIM*NB)
#define WS_BEST  (WS_WIN + 32)
#define WS_GMAX  (WS_BEST + 32)
#define WS_GSUM  (WS_GMAX + 32)
#define WS_GARG  (WS_GSUM + 32)
#define WS_WH    (WS_GARG + 32)          // W1m hi: 65536 bf16
#define WS_WL    (WS_WH + 32768)         // W1m lo

#define C2 2.8853900817779268f   // 2*log2(e): e^{2x} = 2^(C2*x)

typedef __attribute__((ext_vector_type(8))) short bf16x8;
typedef __attribute__((ext_vector_type(8))) unsigned short ushort8;
typedef __attribute__((ext_vector_type(4))) float f32x4;

__device__ inline unsigned short f2bf(float x) {      // RNE f32 -> bf16
  unsigned u = __float_as_uint(x);
  return (unsigned short)((u + 0x7fffu + ((u >> 16) & 1u)) >> 16);
}
__device__ inline float bf2f(unsigned short h) {
  return __uint_as_float(((unsigned)h) << 16);
}

// K1: blocks 0..31: Ex[b][f] = 2^(C2*(b1[f] + sum_k input[b][k]*W1[f*512+k])); w2n = -2*W2
//     blocks 32..95: split W1m into bf16 hi/lo arrays
__global__ __launch_bounds__(256) void k1_prep(const float* __restrict__ input,
                                               const float* __restrict__ W1,
                                               const float* __restrict__ b1,
                                               const float* __restrict__ W2,
                                               float* __restrict__ Ex,
                                               float* __restrict__ w2n,
                                               unsigned short* __restrict__ wh,
                                               unsigned short* __restrict__ wl) {
  if (blockIdx.x < BDIM) {
    const int b = blockIdx.x, f = threadIdx.x;
    const float* in = input + b * FDIM;
    const float* w  = W1 + (size_t)f * 512;
    float acc = b1[f];
    #pragma unroll 8
    for (int k = 0; k < FDIM; k += 4) {
      float4 iv = *(const float4*)(in + k);
      float4 wv = *(const float4*)(w + k);
      acc = fmaf(iv.x, wv.x, acc); acc = fmaf(iv.y, wv.y, acc);
      acc = fmaf(iv.z, wv.z, acc); acc = fmaf(iv.w, wv.w, acc);
    }
    Ex[b * FDIM + f] = __builtin_amdgcn_exp2f(acc * C2);
    if (b == 0) w2n[f] = -2.0f * W2[f];
  } else {
    int id = ((blockIdx.x - BDIM) * 256 + threadIdx.x) * 4;   // 0..65532
    int f = id >> 8, c = id & 255;
    float4 v = *(const float4*)(W1 + (size_t)f * 512 + 256 + c);
    float xs[4] = {v.x, v.y, v.z, v.w};
    #pragma unroll
    for (int e = 0; e < 4; ++e) {
      unsigned short h = f2bf(xs[e]);
      wh[id + e] = h;
      wl[id + e] = f2bf(xs[e] - bf2f(h));
    }
  }
}

// K23: fused k2_mfma + k3_score + out-copy.
// Phase 1 (= old k2): hm = memory . W1m^T via bf16-split MFMA, 64 m x 256 f
//   per block, em = 2^(C2*hm) kept ON-CHIP: epilogue writes the tile into LDS
//   as emT[f][m] (row pad 68 floats -> phase-2 reads are 2-way/free).
// Phase 2 (= old k3): 8 waves x 4 b, lane = m. Per f: ds_read_b32 em (LDS,
//   ~120cy latency vs ~500cy L3 in the old global EmT path) + SGPR-uniform
//   w2n/Ex + 4x(fma, rcp, fma). No 32 MB EmT write + re-read.
// Tail: out[m0..m0+63][:] = memory rows (k0_copy folded; rows are L3-hot).
__global__ __launch_bounds__(512, 4) void k23_fused(const float* __restrict__ mem,
                                                    const unsigned short* __restrict__ wh,
                                                    const unsigned short* __restrict__ wl,
                                                    const float* __restrict__ Ex,
                                                    const float* __restrict__ w2n,
                                                    float* __restrict__ pmax,
                                                    float* __restrict__ psum,
                                                    int* __restrict__ parg,
                                                    float* __restrict__ out) {
  __shared__ __align__(16) char smem[69632];          // max(51200 staging, 256*68*4 emT)
  unsigned short* AH = (unsigned short*)(smem);        // 64*40  = 5120 B
  unsigned short* AL = (unsigned short*)(smem + 5120);
  unsigned short* BH = (unsigned short*)(smem + 10240);// 256*40 = 20480 B
  unsigned short* BL = (unsigned short*)(smem + 30720);
  float* emT = (float*)smem;                           // phase 2: [256][68] f32

  const int tid = threadIdx.x;
  const int lane = tid & 63, wid = tid >> 6;
  const int m0 = blockIdx.x * 64;
  const int rb = lane & 15, g8 = (lane >> 4) * 8;
  const int mh = wid & 1;        // m-half (32 rows)
  const int fq = wid >> 1;       // f-quarter (64 cols)

  f32x4 acc[2][4];
  #pragma unroll
  for (int i = 0; i < 2; ++i)
    #pragma unroll
    for (int j = 0; j < 4; ++j) acc[i][j] = (f32x4){0.f, 0.f, 0.f, 0.f};

  for (int s = 0; s < 8; ++s) {
    const int k0 = s * 32;
    __syncthreads();   // prior frag reads complete
    if (tid < 256) {   // stage A: 64 rows x 32 k, split to hi/lo
      int r = tid >> 2, c8 = (tid & 3) * 8;
      float4 a0 = *(const float4*)(mem + (size_t)(m0 + r) * 256 + k0 + c8);
      float4 a1 = *(const float4*)(mem + (size_t)(m0 + r) * 256 + k0 + c8 + 4);
      float xs[8] = {a0.x, a0.y, a0.z, a0.w, a1.x, a1.y, a1.z, a1.w};
      ushort8 ahv, alv;
      #pragma unroll
      for (int e = 0; e < 8; ++e) {
        unsigned short h = f2bf(xs[e]);
        ahv[e] = h;
        alv[e] = f2bf(xs[e] - bf2f(h));
      }
      *(ushort8*)&AH[r * 40 + c8] = ahv;
      *(ushort8*)&AL[r * 40 + c8] = alv;
    } else {           // stage B: 256 rows x 32 k (pre-split, L2-resident)
      int t2 = tid - 256;
      #pragma unroll
      for (int q = 0; q < 4; ++q) {
        int id = q * 256 + t2, br = id >> 2, bc = (id & 3) * 8;
        *(uint4*)&BH[br * 40 + bc] = *(const uint4*)(wh + (size_t)br * 256 + k0 + bc);
        *(uint4*)&BL[br * 40 + bc] = *(const uint4*)(wl + (size_t)br * 256 + k0 + bc);
      }
    }
    __syncthreads();

    bf16x8 fah[2], fal[2], fbh[4], fbl[4];
    #pragma unroll
    for (int i = 0; i < 2; ++i) {
      fah[i] = *(const bf16x8*)&AH[(mh * 32 + i * 16 + rb) * 40 + g8];
      fal[i] = *(const bf16x8*)&AL[(mh * 32 + i * 16 + rb) * 40 + g8];
    }
    #pragma unroll
    for (int j = 0; j < 4; ++j) {
      fbh[j] = *(const bf16x8*)&BH[(fq * 64 + j * 16 + rb) * 40 + g8];
      fbl[j] = *(const bf16x8*)&BL[(fq * 64 + j * 16 + rb) * 40 + g8];
    }
    #pragma unroll
    for (int i = 0; i < 2; ++i)
      #pragma unroll
      for (int j = 0; j < 4; ++j) {
        acc[i][j] = __builtin_amdgcn_mfma_f32_16x16x32_bf16(fah[i], fbh[j], acc[i][j], 0, 0, 0);
        acc[i][j] = __builtin_amdgcn_mfma_f32_16x16x32_bf16(fah[i], fbl[j], acc[i][j], 0, 0, 0);
        acc[i][j] = __builtin_amdgcn_mfma_f32_16x16x32_bf16(fal[i], fbh[j], acc[i][j], 0, 0, 0);
      }
  }

  // Epilogue: em -> LDS (transposed [f][m], pad 68). D frag: f = fq*64+j*16+rb,
  // m_local = mh*32+i*16+(lane>>4)*4 + r (r = reg idx -> one float4 along m).
  // Row stride 68 floats => phase-2 read banks (4f+lane)&31: 2 lanes/bank, free.
  __syncthreads();   // all frag reads done before staging buffers are overwritten
  #pragma unroll
  for (int j = 0; j < 4; ++j)
    #pragma unroll
    for (int i = 0; i < 2; ++i) {
      const int fl = fq * 64 + j * 16 + rb;
      const int mloc = mh * 32 + i * 16 + (lane >> 4) * 4;
      float4 v;
      v.x = __builtin_amdgcn_exp2f(acc[i][j][0] * C2);
      v.y = __builtin_amdgcn_exp2f(acc[i][j][1] * C2);
      v.z = __builtin_amdgcn_exp2f(acc[i][j][2] * C2);
      v.w = __builtin_amdgcn_exp2f(acc[i][j][3] * C2);
      *(float4*)(emT + fl * 68 + mloc) = v;
    }
  __syncthreads();

  // Phase 2: score. Wave owns 4 b; lane = local m. Per f: one LDS read +
  // SGPR-uniform w2n/Ex + 4x(fma, rcp, fma).
  const int wuid = __builtin_amdgcn_readfirstlane(wid);  // 0..7
  const float* ex0 = Ex + (size_t)(wuid * 4 + 0) * FDIM;
  const float* ex1 = Ex + (size_t)(wuid * 4 + 1) * FDIM;
  const float* ex2 = Ex + (size_t)(wuid * 4 + 2) * FDIM;
  const float* ex3 = Ex + (size_t)(wuid * 4 + 3) * FDIM;

  float acc0 = 0.f, acc1 = 0.f, acc2 = 0.f, acc3 = 0.f;
  #pragma unroll 8
  for (int f = 0; f < FDIM; ++f) {
    float em = emT[f * 68 + lane];
    float w  = w2n[f];                    // uniform -> SGPR
    float u;
    u = fmaf(em, ex0[f], 1.f); acc0 = fmaf(w, __builtin_amdgcn_rcpf(u), acc0);
    u = fmaf(em, ex1[f], 1.f); acc1 = fmaf(w, __builtin_amdgcn_rcpf(u), acc1);
    u = fmaf(em, ex2[f], 1.f); acc2 = fmaf(w, __builtin_amdgcn_rcpf(u), acc2);
    u = fmaf(em, ex3[f], 1.f); acc3 = fmaf(w, __builtin_amdgcn_rcpf(u), acc3);
  }

  // wave reduce per owned b: max+argmax over 64 m lanes, then sumexp
  float accb[4] = {acc0, acc1, acc2, acc3};
  const int blk = blockIdx.x;
  #pragma unroll
  for (int bi = 0; bi < 4; ++bi) {
    float s = accb[bi]; int idx = m0 + lane;
    #pragma unroll
    for (int off = 32; off > 0; off >>= 1) {
      float so = __shfl_xor(s, off);
      int   io = __shfl_xor(idx, off);
      if (so > s || (so == s && io < idx)) { s = so; idx = io; }
    }
    float ex = __expf(accb[bi] - s);
    #pragma unroll
    for (int off = 32; off > 0; off >>= 1) ex += __shfl_xor(ex, off);
    if (lane == 0) {
      int b = wuid * 4 + bi;
      pmax[b * NB + blk] = s;
      psum[b * NB + blk] = ex;
      parg[b * NB + blk] = idx;
    }
  }

  // Tail: out = memory for this block's 64 rows (k0_copy folded; src L3-hot).
  {
    const float4* src = (const float4*)(mem + (size_t)m0 * FDIM);
    float4* dst = (float4*)(out + (size_t)m0 * FDIM);
    #pragma unroll
    for (int i = 0; i < 8; ++i) dst[tid + i * 512] = src[tid + i * 512];
  }
}

// K4a: per-b parallel merge of NB partials (32 blocks x 256 thr)
__global__ __launch_bounds__(256) void k4a_reduce(const float* __restrict__ pmax,
                                                  const float* __restrict__ psum,
                                                  const int* __restrict__ parg,
                                                  float* __restrict__ gmax,
                                                  float* __restrict__ gsum,
                                                  int* __restrict__ garg) {
  __shared__ float sm[4], ss[4];
  __shared__ int   sa[4];
  const int b = blockIdx.x, tid = threadIdx.x;
  float cm = -3.0e38f, cs = 0.f; int ca = 0x7fffffff;
  #pragma unroll
  for (int t = 0; t < NB / 256; ++t) {
    int i = t * 256 + tid;
    float s = pmax[b * NB + i];
    float p = psum[b * NB + i];
    int   a = parg[b * NB + i];
    if (s > cm)      { cs = cs * __expf(cm - s) + p; cm = s; ca = a; }
    else if (s == cm){ cs += p; if (a < ca) ca = a; }
    else             { cs += p * __expf(s - cm); }
  }
  #pragma unroll
  for (int off = 32; off > 0; off >>= 1) {
    float om = __shfl_xor(cm, off);
    float os = __shfl_xor(cs, off);
    int   oa = __shfl_xor(ca, off);
    if (om > cm)      { cs = cs * __expf(cm - om) + os; cm = om; ca = oa; }
    else if (om == cm){ cs += os; if (oa < ca) ca = oa; }
    else              { cs += os * __expf(om - cm); }
  }
  if ((tid & 63) == 0) { sm[tid >> 6] = cm; ss[tid >> 6] = cs; sa[tid >> 6] = ca; }
  __syncthreads();
  if (tid == 0) {
    cm = sm[0]; cs = ss[0]; ca = sa[0];
    for (int w = 1; w < 4; ++w) {
      float om = sm[w], os = ss[w]; int oa = sa[w];
      if (om > cm)      { cs = cs * __expf(cm - om) + os; cm = om; ca = oa; }
      else if (om == cm){ cs += os; if (oa < ca) ca = oa; }
      else              { cs += os * __expf(om - cm); }
    }
    gmax[b] = cm; gsum[b] = cs; garg[b] = ca;
  }
}

// K4b: mask + winner-per-slot dedup (winner = LARGEST masked b per slot)
__global__ __launch_bounds__(64) void k4b_select(const float* __restrict__ gsum,
                                                 const int* __restrict__ garg,
                                                 const float* __restrict__ thr_p,
                                                 int* __restrict__ win,
                                                 int* __restrict__ best) {
  const int tid = threadIdx.x;
  if (tid < BDIM) {
    const float thr = *thr_p;
    int me = garg[tid];
    int w = (1.0f / gsum[tid] > thr) ? 1 : 0;   // maxw = 1/sumexp
    if (w) {
      for (int b2 = tid + 1; b2 < BDIM; ++b2)
        if ((1.0f / gsum[b2] > thr) && garg[b2] == me) { w = 0; break; }
    }
    win[tid] = w; best[tid] = me;
  }
}

// K6: patch winning rows: out[best[b]] = input[b]
__global__ __launch_bounds__(64) void k6_patch(const float* __restrict__ input,
                                               const int* __restrict__ win,
                                               const int* __restrict__ best,
                                               float* __restrict__ out) {
  const int b = blockIdx.x;
  if (!win[b]) return;
  const int m = best[b];
  const int t = threadIdx.x;
  *(float4*)(out + (size_t)m * 256 + t * 4) = *(const float4*)(input + (size_t)b * 256 + t * 4);
}

extern "C" void kernel_launch(void* const* d_in, const int* in_sizes, int n_in,
                              void* d_out, int out_size, void* d_ws, size_t ws_size,
                              hipStream_t stream) {
  const float* input  = (const float*)d_in[0];
  const float* memory = (const float*)d_in[1];
  const float* W1     = (const float*)d_in[2];
  const float* b1     = (const float*)d_in[3];
  const float* W2     = (const float*)d_in[4];
  // d_in[5] = b2: constant score shift, softmax/argmax/maxw invariant -> unused
  const float* thr    = (const float*)d_in[6];

  float* ws   = (float*)d_ws;
  float* Ex   = ws + WS_EX;
  float* w2n  = ws + WS_W2N;
  float* pmax = ws + WS_PMAX;
  float* psum = ws + WS_PSUM;
  int*   parg = (int*)(ws + WS_PARG);
  int*   win  = (int*)(ws + WS_WIN);
  int*   best = (int*)(ws + WS_BEST);
  float* gmax = ws + WS_GMAX;
  float* gsum = ws + WS_GSUM;
  int*   garg = (int*)(ws + WS_GARG);
  unsigned short* wh = (unsigned short*)(ws + WS_WH);
  unsigned short* wl = (unsigned short*)(ws + WS_WL);
  float* out  = (float*)d_out;

  hipLaunchKernelGGL(k1_prep,    dim3(BDIM + 64), dim3(256), 0, stream, input, W1, b1, W2, Ex, w2n, wh, wl);
  hipLaunchKernelGGL(k23_fused,  dim3(MDIM / 64), dim3(512), 0, stream, memory, wh, wl, Ex, w2n, pmax, psum, parg, out);
  hipLaunchKernelGGL(k4a_reduce, dim3(BDIM),      dim3(256), 0, stream, pmax, psum, parg, gmax, gsum, garg);
  hipLaunchKernelGGL(k4b_select, dim3(1),         dim3(64),  0, stream, gsum, garg, thr, win, best);
  hipLaunchKernelGGL(k6_patch,   dim3(BDIM),      dim3(64),  0, stream, input, win, best, out);
}

// Round 2
// 71.712 us; speedup vs baseline: 1.4406x; 1.0681x over previous
//
#include <hip/hip_runtime.h>

// Problem constants
#define FDIM 256
#define BDIM 32
#define MDIM 32768
#define NB   512        // m-tiles (64 m each); one partial per (b, tile)

// ws layout (float units)
#define WS_EM    0                       // (unused after fusion; kept for layout stability)
#define WS_EX    (WS_EM + MDIM*FDIM)
#define WS_W2N   (WS_EX + BDIM*FDIM)
#define WS_PMAX  (WS_W2N + FDIM)
#define WS_PSUM  (WS_PMAX + BDIM*NB)
#define WS_PARG  (WS_PSUM + BDIM*NB)
#define WS_WIN   (WS_PARG + BDIM*NB)
#define WS_BEST  (WS_WIN + 32)
#define WS_GMAX  (WS_BEST + 32)
#define WS_GSUM  (WS_GMAX + 32)
#define WS_GARG  (WS_GSUM + 32)
#define WS_WH    (WS_GARG + 32)          // W1m hi: 65536 bf16
#define WS_WL    (WS_WH + 32768)         // W1m lo

#define C2 2.8853900817779268f   // 2*log2(e): e^{2x} = 2^(C2*x)

typedef __attribute__((ext_vector_type(8))) short bf16x8;
typedef __attribute__((ext_vector_type(8))) unsigned short ushort8;
typedef __attribute__((ext_vector_type(4))) float f32x4;

__device__ inline unsigned short f2bf(float x) {      // RNE f32 -> bf16
  unsigned u = __float_as_uint(x);
  return (unsigned short)((u + 0x7fffu + ((u >> 16) & 1u)) >> 16);
}
__device__ inline float bf2f(unsigned short h) {
  return __uint_as_float(((unsigned)h) << 16);
}

// K1: blocks 0..31: Ex[b][f] = 2^(C2*(b1[f] + sum_k input[b][k]*W1[f*512+k])); w2n = -2*W2
//     blocks 32..95: split W1m into bf16 hi/lo arrays
__global__ __launch_bounds__(256) void k1_prep(const float* __restrict__ input,
                                               const float* __restrict__ W1,
                                               const float* __restrict__ b1,
                                               const float* __restrict__ W2,
                                               float* __restrict__ Ex,
                                               float* __restrict__ w2n,
                                               unsigned short* __restrict__ wh,
                                               unsigned short* __restrict__ wl) {
  if (blockIdx.x < BDIM) {
    const int b = blockIdx.x, f = threadIdx.x;
    const float* in = input + b * FDIM;
    const float* w  = W1 + (size_t)f * 512;
    float acc = b1[f];
    #pragma unroll 8
    for (int k = 0; k < FDIM; k += 4) {
      float4 iv = *(const float4*)(in + k);
      float4 wv = *(const float4*)(w + k);
      acc = fmaf(iv.x, wv.x, acc); acc = fmaf(iv.y, wv.y, acc);
      acc = fmaf(iv.z, wv.z, acc); acc = fmaf(iv.w, wv.w, acc);
    }
    Ex[b * FDIM + f] = __builtin_amdgcn_exp2f(acc * C2);
    if (b == 0) w2n[f] = -2.0f * W2[f];
  } else {
    int id = ((blockIdx.x - BDIM) * 256 + threadIdx.x) * 4;   // 0..65532
    int f = id >> 8, c = id & 255;
    float4 v = *(const float4*)(W1 + (size_t)f * 512 + 256 + c);
    float xs[4] = {v.x, v.y, v.z, v.w};
    #pragma unroll
    for (int e = 0; e < 4; ++e) {
      unsigned short h = f2bf(xs[e]);
      wh[id + e] = h;
      wl[id + e] = f2bf(xs[e] - bf2f(h));
    }
  }
}

// K23: fused k2_mfma + k3_score + out-copy.
// Phase 1 (= old k2): hm = memory . W1m^T via bf16-split MFMA, 64 m x 256 f
//   per block, em = 2^(C2*hm) kept ON-CHIP in LDS as emT[f][m] (pad 68).
//   The staging loads of `memory` double as the out-copy (out = memory rows
//   written at load time; k6_patch overwrites winners later, stream-ordered).
// Phase 2 (= old k3): 8 waves x 4 b, lane = m. 4-f partial-fraction grouping:
//   sum_i w_i/u_i = num/den with den = u0u1u2u3 -> ONE v_rcp per 4 f per b
//   (14 VALU + 1 rcp = 36 cyc vs 48 cyc for 4x(fma,rcp,fma)).
__global__ __launch_bounds__(512, 4) void k23_fused(const float* __restrict__ mem,
                                                    const unsigned short* __restrict__ wh,
                                                    const unsigned short* __restrict__ wl,
                                                    const float* __restrict__ Ex,
                                                    const float* __restrict__ w2n,
                                                    float* __restrict__ pmax,
                                                    float* __restrict__ psum,
                                                    int* __restrict__ parg,
                                                    float* __restrict__ out) {
  __shared__ __align__(16) char smem[69632];          // max(51200 staging, 256*68*4 emT)
  unsigned short* AH = (unsigned short*)(smem);        // 64*40  = 5120 B
  unsigned short* AL = (unsigned short*)(smem + 5120);
  unsigned short* BH = (unsigned short*)(smem + 10240);// 256*40 = 20480 B
  unsigned short* BL = (unsigned short*)(smem + 30720);
  float* emT = (float*)smem;                           // phase 2: [256][68] f32

  const int tid = threadIdx.x;
  const int lane = tid & 63, wid = tid >> 6;
  const int m0 = blockIdx.x * 64;
  const int rb = lane & 15, g8 = (lane >> 4) * 8;
  const int mh = wid & 1;        // m-half (32 rows)
  const int fq = wid >> 1;       // f-quarter (64 cols)

  f32x4 acc[2][4];
  #pragma unroll
  for (int i = 0; i < 2; ++i)
    #pragma unroll
    for (int j = 0; j < 4; ++j) acc[i][j] = (f32x4){0.f, 0.f, 0.f, 0.f};

  for (int s = 0; s < 8; ++s) {
    const int k0 = s * 32;
    __syncthreads();   // prior frag reads complete
    if (tid < 256) {   // stage A: 64 rows x 32 k, split to hi/lo; store out=mem
      int r = tid >> 2, c8 = (tid & 3) * 8;
      const float* mrow = mem + (size_t)(m0 + r) * 256 + k0 + c8;
      float4 a0 = *(const float4*)(mrow);
      float4 a1 = *(const float4*)(mrow + 4);
      float* orow = out + (size_t)(m0 + r) * 256 + k0 + c8;
      *(float4*)(orow)     = a0;             // folded k0_copy (fire-and-forget)
      *(float4*)(orow + 4) = a1;
      float xs[8] = {a0.x, a0.y, a0.z, a0.w, a1.x, a1.y, a1.z, a1.w};
      ushort8 ahv, alv;
      #pragma unroll
      for (int e = 0; e < 8; ++e) {
        unsigned short h = f2bf(xs[e]);
        ahv[e] = h;
        alv[e] = f2bf(xs[e] - bf2f(h));
      }
      *(ushort8*)&AH[r * 40 + c8] = ahv;
      *(ushort8*)&AL[r * 40 + c8] = alv;
    } else {           // stage B: 256 rows x 32 k (pre-split, L2-resident)
      int t2 = tid - 256;
      #pragma unroll
      for (int q = 0; q < 4; ++q) {
        int id = q * 256 + t2, br = id >> 2, bc = (id & 3) * 8;
        *(uint4*)&BH[br * 40 + bc] = *(const uint4*)(wh + (size_t)br * 256 + k0 + bc);
        *(uint4*)&BL[br * 40 + bc] = *(const uint4*)(wl + (size_t)br * 256 + k0 + bc);
      }
    }
    __syncthreads();

    bf16x8 fah[2], fal[2], fbh[4], fbl[4];
    #pragma unroll
    for (int i = 0; i < 2; ++i) {
      fah[i] = *(const bf16x8*)&AH[(mh * 32 + i * 16 + rb) * 40 + g8];
      fal[i] = *(const bf16x8*)&AL[(mh * 32 + i * 16 + rb) * 40 + g8];
    }
    #pragma unroll
    for (int j = 0; j < 4; ++j) {
      fbh[j] = *(const bf16x8*)&BH[(fq * 64 + j * 16 + rb) * 40 + g8];
      fbl[j] = *(const bf16x8*)&BL[(fq * 64 + j * 16 + rb) * 40 + g8];
    }
    #pragma unroll
    for (int i = 0; i < 2; ++i)
      #pragma unroll
      for (int j = 0; j < 4; ++j) {
        acc[i][j] = __builtin_amdgcn_mfma_f32_16x16x32_bf16(fah[i], fbh[j], acc[i][j], 0, 0, 0);
        acc[i][j] = __builtin_amdgcn_mfma_f32_16x16x32_bf16(fah[i], fbl[j], acc[i][j], 0, 0, 0);
        acc[i][j] = __builtin_amdgcn_mfma_f32_16x16x32_bf16(fal[i], fbh[j], acc[i][j], 0, 0, 0);
      }
  }

  // Epilogue: em -> LDS (transposed [f][m], pad 68). D frag: f = fq*64+j*16+rb,
  // m_local = mh*32+i*16+(lane>>4)*4 + r (r = reg idx -> one float4 along m).
  __syncthreads();   // all frag reads done before staging buffers are overwritten
  #pragma unroll
  for (int j = 0; j < 4; ++j)
    #pragma unroll
    for (int i = 0; i < 2; ++i) {
      const int fl = fq * 64 + j * 16 + rb;
      const int mloc = mh * 32 + i * 16 + (lane >> 4) * 4;
      float4 v;
      v.x = __builtin_amdgcn_exp2f(acc[i][j][0] * C2);
      v.y = __builtin_amdgcn_exp2f(acc[i][j][1] * C2);
      v.z = __builtin_amdgcn_exp2f(acc[i][j][2] * C2);
      v.w = __builtin_amdgcn_exp2f(acc[i][j][3] * C2);
      *(float4*)(emT + fl * 68 + mloc) = v;
    }
  __syncthreads();

  // Phase 2: score. Wave owns 4 b; lane = local m. 4-f groups share one rcp:
  //   sum_{i=0..3} w_i/u_i = [(w0u1+w1u0)u2u3 + (w2u3+w3u2)u0u1] / (u0u1u2u3)
  // u ranges [1, ~1+e^8] -> den <= ~1e14, no overflow; rounding ~2^-20 rel,
  // far below the bf16-split noise already in em.
  const int wuid = __builtin_amdgcn_readfirstlane(wid);  // 0..7
  const float* ex0 = Ex + (size_t)(wuid * 4 + 0) * FDIM;
  const float* ex1 = Ex + (size_t)(wuid * 4 + 1) * FDIM;
  const float* ex2 = Ex + (size_t)(wuid * 4 + 2) * FDIM;
  const float* ex3 = Ex + (size_t)(wuid * 4 + 3) * FDIM;

  float acc0 = 0.f, acc1 = 0.f, acc2 = 0.f, acc3 = 0.f;
  #pragma unroll 2
  for (int f = 0; f < FDIM; f += 4) {
    float e0 = emT[(f + 0) * 68 + lane];
    float e1 = emT[(f + 1) * 68 + lane];
    float e2 = emT[(f + 2) * 68 + lane];
    float e3 = emT[(f + 3) * 68 + lane];
    float w0 = w2n[f + 0], w1 = w2n[f + 1];   // uniform -> SGPR
    float w2 = w2n[f + 2], w3 = w2n[f + 3];
    #define SCORE4(exP, accV)                                            \
    {                                                                    \
      float u0 = fmaf(e0, exP[f + 0], 1.f);                              \
      float u1 = fmaf(e1, exP[f + 1], 1.f);                              \
      float u2 = fmaf(e2, exP[f + 2], 1.f);                              \
      float u3 = fmaf(e3, exP[f + 3], 1.f);                              \
      float p01 = u0 * u1, p23 = u2 * u3;                                \
      float den = p01 * p23;                                             \
      float t0 = fmaf(w1, u0, w0 * u1);                                  \
      float t1 = fmaf(w3, u2, w2 * u3);                                  \
      float num = fmaf(t1, p01, t0 * p23);                               \
      accV = fmaf(num, __builtin_amdgcn_rcpf(den), accV);                \
    }
    SCORE4(ex0, acc0)
    SCORE4(ex1, acc1)
    SCORE4(ex2, acc2)
    SCORE4(ex3, acc3)
    #undef SCORE4
  }

  // wave reduce per owned b: max+argmax over 64 m lanes, then sumexp
  float accb[4] = {acc0, acc1, acc2, acc3};
  const int blk = blockIdx.x;
  #pragma unroll
  for (int bi = 0; bi < 4; ++bi) {
    float s = accb[bi]; int idx = m0 + lane;
    #pragma unroll
    for (int off = 32; off > 0; off >>= 1) {
      float so = __shfl_xor(s, off);
      int   io = __shfl_xor(idx, off);
      if (so > s || (so == s && io < idx)) { s = so; idx = io; }
    }
    float ex = __expf(accb[bi] - s);
    #pragma unroll
    for (int off = 32; off > 0; off >>= 1) ex += __shfl_xor(ex, off);
    if (lane == 0) {
      int b = wuid * 4 + bi;
      pmax[b * NB + blk] = s;
      psum[b * NB + blk] = ex;
      parg[b * NB + blk] = idx;
    }
  }
}

// K4a: per-b parallel merge of NB partials (32 blocks x 256 thr)
__global__ __launch_bounds__(256) void k4a_reduce(const float* __restrict__ pmax,
                                                  const float* __restrict__ psum,
                                                  const int* __restrict__ parg,
                                                  float* __restrict__ gmax,
                                                  float* __restrict__ gsum,
                                                  int* __restrict__ garg) {
  __shared__ float sm[4], ss[4];
  __shared__ int   sa[4];
  const int b = blockIdx.x, tid = threadIdx.x;
  float cm = -3.0e38f, cs = 0.f; int ca = 0x7fffffff;
  #pragma unroll
  for (int t = 0; t < NB / 256; ++t) {
    int i = t * 256 + tid;
    float s = pmax[b * NB + i];
    float p = psum[b * NB + i];
    int   a = parg[b * NB + i];
    if (s > cm)      { cs = cs * __expf(cm - s) + p; cm = s; ca = a; }
    else if (s == cm){ cs += p; if (a < ca) ca = a; }
    else             { cs += p * __expf(s - cm); }
  }
  #pragma unroll
  for (int off = 32; off > 0; off >>= 1) {
    float om = __shfl_xor(cm, off);
    float os = __shfl_xor(cs, off);
    int   oa = __shfl_xor(ca, off);
    if (om > cm)      { cs = cs * __expf(cm - om) + os; cm = om; ca = oa; }
    else if (om == cm){ cs += os; if (oa < ca) ca = oa; }
    else              { cs += os * __expf(om - cm); }
  }
  if ((tid & 63) == 0) { sm[tid >> 6] = cm; ss[tid >> 6] = cs; sa[tid >> 6] = ca; }
  __syncthreads();
  if (tid == 0) {
    cm = sm[0]; cs = ss[0]; ca = sa[0];
    for (int w = 1; w < 4; ++w) {
      float om = sm[w], os = ss[w]; int oa = sa[w];
      if (om > cm)      { cs = cs * __expf(cm - om) + os; cm = om; ca = oa; }
      else if (om == cm){ cs += os; if (oa < ca) ca = oa; }
      else              { cs += os * __expf(om - cm); }
    }
    gmax[b] = cm; gsum[b] = cs; garg[b] = ca;
  }
}

// K4b: mask + winner-per-slot dedup (winner = LARGEST masked b per slot)
__global__ __launch_bounds__(64) void k4b_select(const float* __restrict__ gsum,
                                                 const int* __restrict__ garg,
                                                 const float* __restrict__ thr_p,
                                                 int* __restrict__ win,
                                                 int* __restrict__ best) {
  const int tid = threadIdx.x;
  if (tid < BDIM) {
    const float thr = *thr_p;
    int me = garg[tid];
    int w = (1.0f / gsum[tid] > thr) ? 1 : 0;   // maxw = 1/sumexp
    if (w) {
      for (int b2 = tid + 1; b2 < BDIM; ++b2)
        if ((1.0f / gsum[b2] > thr) && garg[b2] == me) { w = 0; break; }
    }
    win[tid] = w; best[tid] = me;
  }
}

// K6: patch winning rows: out[best[b]] = input[b]
__global__ __launch_bounds__(64) void k6_patch(const float* __restrict__ input,
                                               const int* __restrict__ win,
                                               const int* __restrict__ best,
                                               float* __restrict__ out) {
  const int b = blockIdx.x;
  if (!win[b]) return;
  const int m = best[b];
  const int t = threadIdx.x;
  *(float4*)(out + (size_t)m * 256 + t * 4) = *(const float4*)(input + (size_t)b * 256 + t * 4);
}

extern "C" void kernel_launch(void* const* d_in, const int* in_sizes, int n_in,
                              void* d_out, int out_size, void* d_ws, size_t ws_size,
                              hipStream_t stream) {
  const float* input  = (const float*)d_in[0];
  const float* memory = (const float*)d_in[1];
  const float* W1     = (const float*)d_in[2];
  const float* b1     = (const float*)d_in[3];
  const float* W2     = (const float*)d_in[4];
  // d_in[5] = b2: constant score shift, softmax/argmax/maxw invariant -> unused
  const float* thr    = (const float*)d_in[6];

  float* ws   = (float*)d_ws;
  float* Ex   = ws + WS_EX;
  float* w2n  = ws + WS_W2N;
  float* pmax = ws + WS_PMAX;
  float* psum = ws + WS_PSUM;
  int*   parg = (int*)(ws + WS_PARG);
  int*   win  = (int*)(ws + WS_WIN);
  int*   best = (int*)(ws + WS_BEST);
  float* gmax = ws + WS_GMAX;
  float* gsum = ws + WS_GSUM;
  int*   garg = (int*)(ws + WS_GARG);
  unsigned short* wh = (unsigned short*)(ws + WS_WH);
  unsigned short* wl = (unsigned short*)(ws + WS_WL);
  float* out  = (float*)d_out;

  hipLaunchKernelGGL(k1_prep,    dim3(BDIM + 64), dim3(256), 0, stream, input, W1, b1, W2, Ex, w2n, wh, wl);
  hipLaunchKernelGGL(k23_fused,  dim3(MDIM / 64), dim3(512), 0, stream, memory, wh, wl, Ex, w2n, pmax, psum, parg, out);
  hipLaunchKernelGGL(k4a_reduce, dim3(BDIM),      dim3(256), 0, stream, pmax, psum, parg, gmax, gsum, garg);
  hipLaunchKernelGGL(k4b_select, dim3(1),         dim3(64),  0, stream, gsum, garg, thr, win, best);
  hipLaunchKernelGGL(k6_patch,   dim3(BDIM),      dim3(64),  0, stream, input, win, best, out);
}